// Round 8
// baseline (365.827 us; speedup 1.0000x reference)
//
#include <hip/hip_runtime.h>
#include <cstdint>
#include <math.h>

#define B_ 64
#define S_ 512
#define H_ 1024
#define T_ 24

// readlane: value from lane `sl` (wave-uniform index ok), bitcast through uint
__device__ __forceinline__ float rl_f32(float x, int sl) {
    return __uint_as_float(__builtin_amdgcn_readlane(__float_as_uint(x), sl));
}

// ---------------------------------------------------------------------------
// Kernel 1: emission[b,s,t] = sum_h feats[b,s,h]*W[t,h] + bias[t]
// R8 design: NO LDS, NO barriers, NO W-in-VGPR tricks (R5-R7 lesson: the
// compiler defeats VGPR-cache-of-W schemes; VGPR_Count=32 proved Wreg never
// lived in registers). Each lane streams its own feats row global->VGPR
// (vmcnt); W addresses are wave-uniform (t0 readfirstlane, h loop-uniform)
// -> s_load_dwordx4 on lgkmcnt. The two counters are INDEPENDENT (R4's
// poison was s_load sharing lgkmcnt with ds_read) -> both streams pipeline.
// 512 blocks x 512 thr: 8 waves/block share 64 rows (L1 dedups refetch),
// wave w owns t-trio [3w,3w+3). 4096 waves = 4/SIMD latency hiding.
// Chip VALU total ~10us < HBM floor ~21us -> memory-bound by design.
// ---------------------------------------------------------------------------
__global__ __launch_bounds__(512, 4) void gemm_kernel(const float* __restrict__ feats,
                                                      const float* __restrict__ W,
                                                      const float* __restrict__ bias,
                                                      float* __restrict__ emission) {
    const int tid  = threadIdx.x;
    const int lane = tid & 63;                                   // row within block
    const int w    = __builtin_amdgcn_readfirstlane(tid >> 6);   // wave 0..7
    const int t0   = w * 3;
    const long row = (long)blockIdx.x * 64 + lane;

    const float* fr = feats + row * H_;
    const float* w0 = W + (long)t0 * H_;
    const float* w1 = w0 + H_;
    const float* w2 = w1 + H_;

    float a0 = 0.f, a1 = 0.f, a2 = 0.f;

    float4 cur = *(const float4*)fr;
#pragma unroll 4
    for (int h = 0; h < H_; h += 4) {
        // prefetch next feats quad (independent vmcnt; leads the FMAs)
        float4 nxt;
        if (h + 4 < H_) nxt = *(const float4*)(fr + h + 4);
        else            nxt = float4{0.f, 0.f, 0.f, 0.f};

        // wave-uniform W quads -> s_load_dwordx4 (lgkmcnt, SALU-side)
        const float4 v0 = *(const float4*)(w0 + h);
        const float4 v1 = *(const float4*)(w1 + h);
        const float4 v2 = *(const float4*)(w2 + h);

        a0 = fmaf(cur.x, v0.x, a0); a0 = fmaf(cur.y, v0.y, a0);
        a0 = fmaf(cur.z, v0.z, a0); a0 = fmaf(cur.w, v0.w, a0);
        a1 = fmaf(cur.x, v1.x, a1); a1 = fmaf(cur.y, v1.y, a1);
        a1 = fmaf(cur.z, v1.z, a1); a1 = fmaf(cur.w, v1.w, a1);
        a2 = fmaf(cur.x, v2.x, a2); a2 = fmaf(cur.y, v2.y, a2);
        a2 = fmaf(cur.z, v2.z, a2); a2 = fmaf(cur.w, v2.w, a2);

        cur = nxt;
    }

    float* out = emission + row * T_ + t0;
    out[0] = a0 + bias[t0 + 0];
    out[1] = a1 + bias[t0 + 1];
    out[2] = a2 + bias[t0 + 2];
}

// ---------------------------------------------------------------------------
// Kernel 2: gold-path score per batch. One wave per batch.
// ---------------------------------------------------------------------------
__global__ __launch_bounds__(64) void score_kernel(const float* __restrict__ emission,
                                                   const int* __restrict__ target,
                                                   const int* __restrict__ mask,
                                                   const float* __restrict__ trans,
                                                   float* __restrict__ ws_score) {
    const int b = blockIdx.x;
    const int lane = threadIdx.x;
    float sum = 0.f;
    for (int s = lane; s < S_; s += 64) {
        if (mask[b * S_ + s]) {
            const int tg = target[b * S_ + s];
            float v = emission[((long)b * S_ + s) * T_ + tg];
            if (s > 0) v += trans[target[b * S_ + s - 1] * T_ + tg];
            sum += v;
        }
    }
#pragma unroll
    for (int off = 32; off; off >>= 1) sum += __shfl_down(sum, off);
    if (lane == 0) ws_score[b] = sum;
}

// ---------------------------------------------------------------------------
// Kernel 3: forward algorithm (unchanged from R7 -- counters due next round).
// Pure probability domain; E as 24 named scalars (R6 lesson: arrays spill);
// raw-emission prefetch ring depth 8; renorm once/16 steps by actual q.
// ---------------------------------------------------------------------------
#define DECL_E(i) const float E##i = __expf(trans[(i) * T_ + jj]);
#define FMA4(i0, i1, i2, i3)                                                   \
    s0 = fmaf(rl_f32(q, i0), E##i0, s0);                                       \
    s1 = fmaf(rl_f32(q, i1), E##i1, s1);                                       \
    s2 = fmaf(rl_f32(q, i2), E##i2, s2);                                       \
    s3 = fmaf(rl_f32(q, i3), E##i3, s3);

__global__ __launch_bounds__(64, 1) void scan_kernel(const float* __restrict__ emission,
                                                     const int* __restrict__ mask,
                                                     const float* __restrict__ trans,
                                                     float* __restrict__ ws_logZ) {
    const int b = blockIdx.x;
    const int j = threadIdx.x;          // math lanes j<24; others dummies
    const int jj = j < 24 ? j : 23;

    const float* em = emission + (long)b * S_ * T_;
    const int* mk = mask + b * S_;

    // len = sum(mask row) (prefix-contiguous by construction)
    int mc = 0;
#pragma unroll
    for (int k = 0; k < 8; ++k) mc += mk[j + k * 64];
#pragma unroll
    for (int off = 32; off; off >>= 1) mc += __shfl_xor(mc, off);
    const int len = __builtin_amdgcn_readfirstlane(mc);

    DECL_E(0)  DECL_E(1)  DECL_E(2)  DECL_E(3)  DECL_E(4)  DECL_E(5)
    DECL_E(6)  DECL_E(7)  DECL_E(8)  DECL_E(9)  DECL_E(10) DECL_E(11)
    DECL_E(12) DECL_E(13) DECL_E(14) DECL_E(15) DECL_E(16) DECL_E(17)
    DECL_E(18) DECL_E(19) DECL_E(20) DECL_E(21) DECL_E(22) DECL_E(23)

    float q = (j < 24) ? __expf(em[j]) : 0.f;
    float C = 0.f;

    // prefetch ring of RAW emissions, depth 8 (load leads consume by 8 steps)
    float lb[8];
#pragma unroll
    for (int k = 0; k < 8; ++k) lb[k] = em[(1 + k) * T_ + jj];

    for (int sb = 1; sb < S_; sb += 16) {
#pragma unroll
        for (int k = 0; k < 16; ++k) {
            const int s = sb + k;
            const float X = __expf(lb[k & 7]);   // loaded 8 steps ago: no stall
            const int sp = s + 8;
            lb[k & 7] = (sp < S_) ? em[sp * T_ + jj] : 0.f;

            if (s < len) {               // uniform branch (len in SGPR)
                float s0 = 0.f, s1 = 0.f, s2 = 0.f, s3 = 0.f;
                FMA4(0, 1, 2, 3)
                FMA4(4, 5, 6, 7)
                FMA4(8, 9, 10, 11)
                FMA4(12, 13, 14, 15)
                FMA4(16, 17, 18, 19)
                FMA4(20, 21, 22, 23)
                q = ((s0 + s1) + (s2 + s3)) * X;
            }
        }
        // window renormalization (1/16 amortized on the chain)
        const float r = rl_f32(q, 0);
        q *= (1.0f / r);
        C += __logf(r);
    }

    float ex = (j < 24) ? q : 0.f;
#pragma unroll
    for (int off = 32; off; off >>= 1) ex += __shfl_down(ex, off);
    if (j == 0) ws_logZ[b] = C + __logf(ex);
}

// ---------------------------------------------------------------------------
// Kernel 4: loss = -mean(score - logZ)
// ---------------------------------------------------------------------------
__global__ __launch_bounds__(64) void finalize_kernel(const float* __restrict__ ws_score,
                                                      const float* __restrict__ ws_logZ,
                                                      float* __restrict__ out) {
    const int l = threadIdx.x;
    float v = ws_score[l] - ws_logZ[l];
#pragma unroll
    for (int off = 32; off; off >>= 1) v += __shfl_down(v, off);
    if (l == 0) out[0] = -v * (1.0f / B_);
}

extern "C" void kernel_launch(void* const* d_in, const int* in_sizes, int n_in,
                              void* d_out, int out_size, void* d_ws, size_t ws_size,
                              hipStream_t stream) {
    const float* feats  = (const float*)d_in[0];
    const int*   target = (const int*)d_in[1];
    const int*   mask   = (const int*)d_in[2];
    const float* W      = (const float*)d_in[3];
    const float* bias   = (const float*)d_in[4];
    const float* trans  = (const float*)d_in[5];

    float* out = (float*)d_out;
    float* emission = out + 1;            // output 1, written in place
    float* ws_score = (float*)d_ws;       // 64 floats
    float* ws_logZ  = ws_score + 64;      // 64 floats

    gemm_kernel<<<512, 512, 0, stream>>>(feats, W, bias, emission);
    score_kernel<<<64, 64, 0, stream>>>(emission, target, mask, trans, ws_score);
    scan_kernel<<<64, 64, 0, stream>>>(emission, mask, trans, ws_logZ);
    finalize_kernel<<<1, 64, 0, stream>>>(ws_score, ws_logZ, out);
}